// Round 1
// baseline (287.115 us; speedup 1.0000x reference)
//
#include <hip/hip_runtime.h>
#include <math.h>

#define BATCH   128
#define NUSER   10000
#define NITEM   10000
#define EDIM    64
#define FUDIM   8
#define FIDIM   8
#define INDIM   144   // 2*EDIM + FUDIM + FIDIM

// d_out layout (floats):
// [0, 8192)                      new_user        (B x E)
// [8192, 16384)                  new_item        (B x E)
// [16384, 16384+81920000)        new_user_memory (B x NU x E)
// [16384+81920000, ...)          new_item_memory (B x NI x E)
#define OFF_NI   ((long)BATCH * EDIM)
#define OFF_UM   ((long)2 * BATCH * EDIM)
#define MEM_ELTS ((long)BATCH * NUSER * EDIM)
#define OFF_IM   (OFF_UM + MEM_ELTS)

__global__ void limnet_copy_kernel(const float4* __restrict__ um,
                                   const float4* __restrict__ im,
                                   float4* __restrict__ out_um,
                                   float4* __restrict__ out_im,
                                   long n4) {
    long stride = (long)gridDim.x * blockDim.x;
    for (long i = (long)blockIdx.x * blockDim.x + threadIdx.x; i < n4; i += stride) {
        out_um[i] = um[i];
        out_im[i] = im[i];
    }
}

__global__ __launch_bounds__(64) void limnet_gru_kernel(
    const float* __restrict__ um, const float* __restrict__ im,
    const int* __restrict__ uids, const int* __restrict__ iids,
    const float* __restrict__ ufeat, const float* __restrict__ ifeat,
    const float* __restrict__ u_w_ih, const float* __restrict__ u_b_ih,
    const float* __restrict__ u_b_hh,
    const float* __restrict__ i_w_ih, const float* __restrict__ i_b_ih,
    const float* __restrict__ i_b_hh,
    float* __restrict__ out)
{
    const int unit  = blockIdx.x;   // 0..255
    const int b     = unit >> 1;
    const int which = unit & 1;     // 0 = user GRU, 1 = item GRU
    const int lane  = threadIdx.x;  // 0..63

    __shared__ float x[INDIM];

    const int uid = uids[b];
    const int iid = iids[b];
    const float* ue = um + ((long)b * NUSER + uid) * EDIM;
    const float* ie = im + ((long)b * NITEM + iid) * EDIM;

    // Build the 144-dim concatenated input in LDS.
    if (which == 0) {
        // [user_emb(64), user_feat(8), item_emb(64), item_feat(8)]
        x[lane] = ue[lane];
        x[EDIM + FUDIM + lane] = ie[lane];
        if (lane < FUDIM) x[EDIM + lane] = ufeat[b * FUDIM + lane];
        if (lane < FIDIM) x[EDIM + FUDIM + EDIM + lane] = ifeat[b * FIDIM + lane];
    } else {
        // [item_emb(64), item_feat(8), user_emb(64), user_feat(8)]
        x[lane] = ie[lane];
        x[EDIM + FIDIM + lane] = ue[lane];
        if (lane < FIDIM) x[EDIM + lane] = ifeat[b * FIDIM + lane];
        if (lane < FUDIM) x[EDIM + FIDIM + EDIM + lane] = ufeat[b * FUDIM + lane];
    }
    __syncthreads();

    const float* w   = which ? i_w_ih : u_w_ih;
    const float* bih = which ? i_b_ih : u_b_ih;
    const float* bhh = which ? i_b_hh : u_b_hh;

    // h0 == 0  =>  gh = b_hh exactly; GRU collapses to gates on gi only.
    float gr = bih[lane];
    float gz = bih[EDIM + lane];
    float gn = bih[2 * EDIM + lane];
    const float* wr = w + (long)lane * INDIM;
    const float* wz = w + (long)(EDIM + lane) * INDIM;
    const float* wn = w + (long)(2 * EDIM + lane) * INDIM;
    #pragma unroll 8
    for (int k = 0; k < INDIM; ++k) {
        const float xv = x[k];          // uniform across lanes -> LDS broadcast
        gr = fmaf(wr[k], xv, gr);
        gz = fmaf(wz[k], xv, gz);
        gn = fmaf(wn[k], xv, gn);
    }
    const float r = 1.0f / (1.0f + expf(-(gr + bhh[lane])));
    const float z = 1.0f / (1.0f + expf(-(gz + bhh[EDIM + lane])));
    const float n = tanhf(gn + r * bhh[2 * EDIM + lane]);
    const float h = (1.0f - z) * n;     // + z*h0, h0 == 0

    // L2 normalize across the 64-lane wave.
    float s = h * h;
    #pragma unroll
    for (int off = 32; off; off >>= 1) s += __shfl_xor(s, off, 64);
    const float val = h / fmaxf(sqrtf(s), 1e-12f);

    if (which == 0) {
        out[(long)b * EDIM + lane] = val;
        out[OFF_UM + ((long)b * NUSER + uid) * EDIM + lane] = val;
    } else {
        out[OFF_NI + (long)b * EDIM + lane] = val;
        out[OFF_IM + ((long)b * NITEM + iid) * EDIM + lane] = val;
    }
}

extern "C" void kernel_launch(void* const* d_in, const int* in_sizes, int n_in,
                              void* d_out, int out_size, void* d_ws, size_t ws_size,
                              hipStream_t stream) {
    const float* um    = (const float*)d_in[0];
    const float* im    = (const float*)d_in[1];
    const int*   uids  = (const int*)d_in[2];
    const int*   iids  = (const int*)d_in[3];
    const float* ufeat = (const float*)d_in[4];
    const float* ifeat = (const float*)d_in[5];
    const float* u_w_ih = (const float*)d_in[6];
    // d_in[7] = u_w_hh (unused: h0 == 0)
    const float* u_b_ih = (const float*)d_in[8];
    const float* u_b_hh = (const float*)d_in[9];
    const float* i_w_ih = (const float*)d_in[10];
    // d_in[11] = i_w_hh (unused)
    const float* i_b_ih = (const float*)d_in[12];
    const float* i_b_hh = (const float*)d_in[13];
    float* out = (float*)d_out;

    // 1) Bulk copy of both memories into the output regions (the roofline).
    const long n4 = MEM_ELTS / 4;  // float4 count per memory
    limnet_copy_kernel<<<2048, 256, 0, stream>>>(
        (const float4*)um, (const float4*)im,
        (float4*)(out + OFF_UM), (float4*)(out + OFF_IM), n4);

    // 2) GRU + normalize + scatter-overwrite (tiny; ordered after the copy).
    limnet_gru_kernel<<<BATCH * 2, 64, 0, stream>>>(
        um, im, uids, iids, ufeat, ifeat,
        u_w_ih, u_b_ih, u_b_hh,
        i_w_ih, i_b_ih, i_b_hh,
        out);
}